// Round 4
// baseline (244.376 us; speedup 1.0000x reference)
//
#include <hip/hip_runtime.h>
#include <hip/hip_bf16.h>
#include <math.h>

// out = tanh(x * sigmoid(x)) + sigmoid(x), elementwise fp32, N = 16*2048*4096.
// Memory-bound: 1.073 GB traffic -> ~170 us at the 6.3 TB/s copy ceiling.
// All transcendentals via fast HW ops (v_exp_f32 / v_rcp_f32), branch-free:
//   s = rcp(1 + exp2(-x*log2e));  z = x*s;  tanh(z) = 1 - 2*rcp(exp2(2z*log2e)+1)
// absmax threshold is 3.98e-2; these approximations are ~1e-6 relative.

typedef float vfloat4 __attribute__((ext_vector_type(4)));  // native vector for nontemporal builtins

#define LOG2E 1.44269504088896341f

__device__ __forceinline__ float fast_rcp(float a) {
    return __builtin_amdgcn_rcpf(a);   // v_rcp_f32, ~1 ulp
}

__device__ __forceinline__ float fast_exp(float a) {
    return __builtin_amdgcn_exp2f(a * LOG2E);  // v_exp_f32 computes 2^x
}

__device__ __forceinline__ float act(float v) {
    float s = fast_rcp(1.0f + fast_exp(-v));      // sigmoid(x)
    float z = v * s;                               // silu(x)
    float t = 1.0f - 2.0f * fast_rcp(fast_exp(2.0f * z) + 1.0f);  // tanh(z)
    return t + s;
}

__global__ void __launch_bounds__(256)
dynact_kernel(const vfloat4* __restrict__ x4, vfloat4* __restrict__ o4,
              long long iters, long long stride) {
    const long long base = (long long)blockIdx.x * 256 + threadIdx.x;
    #pragma unroll 4
    for (long long k = 0; k < iters; ++k) {
        const long long i = base + k * stride;
        vfloat4 v = __builtin_nontemporal_load(&x4[i]);
        vfloat4 r;
        r.x = act(v.x);
        r.y = act(v.y);
        r.z = act(v.z);
        r.w = act(v.w);
        __builtin_nontemporal_store(r, &o4[i]);
    }
}

// Remainder float4s beyond iters*stride (guarded).
__global__ void __launch_bounds__(256)
dynact_rem4(const vfloat4* __restrict__ x4, vfloat4* __restrict__ o4,
            long long start, long long n4) {
    long long i = start + (long long)blockIdx.x * blockDim.x + threadIdx.x;
    if (i < n4) {
        vfloat4 v = __builtin_nontemporal_load(&x4[i]);
        vfloat4 r;
        r.x = act(v.x);
        r.y = act(v.y);
        r.z = act(v.z);
        r.w = act(v.w);
        __builtin_nontemporal_store(r, &o4[i]);
    }
}

// Scalar tail if n % 4 != 0 (not the case here).
__global__ void dynact_tail(const float* __restrict__ x, float* __restrict__ out,
                            long long start, long long n) {
    long long i = start + (long long)blockIdx.x * blockDim.x + threadIdx.x;
    if (i < n) out[i] = act(x[i]);
}

extern "C" void kernel_launch(void* const* d_in, const int* in_sizes, int n_in,
                              void* d_out, int out_size, void* d_ws, size_t ws_size,
                              hipStream_t stream) {
    const float* x = (const float*)d_in[0];
    float* out = (float*)d_out;
    const long long n = (long long)in_sizes[0];
    const long long n4 = n >> 2;

    const int block = 256;
    const int grid = 2048;                       // 8 blocks/CU on 256 CUs
    const long long stride = (long long)grid * block;
    const long long iters = n4 / stride;         // 64 exact for this shape

    if (iters > 0) {
        dynact_kernel<<<grid, block, 0, stream>>>(
            (const vfloat4*)x, (vfloat4*)out, iters, stride);
    }
    const long long done4 = iters * stride;
    const long long rem4 = n4 - done4;
    if (rem4 > 0) {
        int g = (int)((rem4 + block - 1) / block);
        dynact_rem4<<<g, block, 0, stream>>>((const vfloat4*)x, (vfloat4*)out, done4, n4);
    }
    const long long done = n4 << 2;
    if (n - done > 0) {
        int g = (int)((n - done + block - 1) / block);
        dynact_tail<<<g, block, 0, stream>>>(x, out, done, n);
    }
}

// Round 5
// 244.194 us; speedup vs baseline: 1.0007x; 1.0007x over previous
//
#include <hip/hip_runtime.h>
#include <hip/hip_bf16.h>
#include <math.h>

// out = tanh(x * sigmoid(x)) + sigmoid(x), elementwise fp32, N = 16*2048*4096.
// Memory-bound: 1.073 GB traffic -> ~170 us at the 6.3 TB/s copy ceiling.
// Fast transcendentals (v_exp_f32 / v_rcp_f32), branch-free. PLAIN cached
// loads/stores — R4 showed nontemporal REGRESSED (244 vs 211 us): nt bypasses
// L2, which is the HBM-request coalescing point on CDNA4.

typedef float vfloat4 __attribute__((ext_vector_type(4)));

#define LOG2E 1.44269504088896341f

__device__ __forceinline__ float fast_rcp(float a) {
    return __builtin_amdgcn_rcpf(a);   // v_rcp_f32, ~1 ulp
}

__device__ __forceinline__ float fast_exp(float a) {
    return __builtin_amdgcn_exp2f(a * LOG2E);  // v_exp_f32 computes 2^x
}

__device__ __forceinline__ float act(float v) {
    float s = fast_rcp(1.0f + fast_exp(-v));      // sigmoid(x)
    float z = v * s;                               // silu(x)
    float t = 1.0f - 2.0f * fast_rcp(fast_exp(2.0f * z) + 1.0f);  // tanh(z)
    return t + s;
}

__global__ void __launch_bounds__(256)
dynact_kernel(const vfloat4* __restrict__ x4, vfloat4* __restrict__ o4,
              long long iters, long long stride) {
    const long long base = (long long)blockIdx.x * 256 + threadIdx.x;
    #pragma unroll 4
    for (long long k = 0; k < iters; ++k) {
        const long long i = base + k * stride;
        vfloat4 v = x4[i];
        vfloat4 r;
        r.x = act(v.x);
        r.y = act(v.y);
        r.z = act(v.z);
        r.w = act(v.w);
        o4[i] = r;
    }
}

// Remainder float4s beyond iters*stride (guarded).
__global__ void __launch_bounds__(256)
dynact_rem4(const vfloat4* __restrict__ x4, vfloat4* __restrict__ o4,
            long long start, long long n4) {
    long long i = start + (long long)blockIdx.x * blockDim.x + threadIdx.x;
    if (i < n4) {
        vfloat4 v = x4[i];
        vfloat4 r;
        r.x = act(v.x);
        r.y = act(v.y);
        r.z = act(v.z);
        r.w = act(v.w);
        o4[i] = r;
    }
}

// Scalar tail if n % 4 != 0 (not the case here).
__global__ void dynact_tail(const float* __restrict__ x, float* __restrict__ out,
                            long long start, long long n) {
    long long i = start + (long long)blockIdx.x * blockDim.x + threadIdx.x;
    if (i < n) out[i] = act(x[i]);
}

extern "C" void kernel_launch(void* const* d_in, const int* in_sizes, int n_in,
                              void* d_out, int out_size, void* d_ws, size_t ws_size,
                              hipStream_t stream) {
    const float* x = (const float*)d_in[0];
    float* out = (float*)d_out;
    const long long n = (long long)in_sizes[0];
    const long long n4 = n >> 2;

    const int block = 256;
    const int grid = 2048;                       // 8 blocks/CU on 256 CUs
    const long long stride = (long long)grid * block;
    const long long iters = n4 / stride;         // 64 exact for this shape

    if (iters > 0) {
        dynact_kernel<<<grid, block, 0, stream>>>(
            (const vfloat4*)x, (vfloat4*)out, iters, stride);
    }
    const long long done4 = iters * stride;
    const long long rem4 = n4 - done4;
    if (rem4 > 0) {
        int g = (int)((rem4 + block - 1) / block);
        dynact_rem4<<<g, block, 0, stream>>>((const vfloat4*)x, (vfloat4*)out, done4, n4);
    }
    const long long done = n4 << 2;
    if (n - done > 0) {
        int g = (int)((n - done + block - 1) / block);
        dynact_tail<<<g, block, 0, stream>>>(x, out, done, n);
    }
}